// Round 6
// baseline (8192.000 us; speedup 1.0000x reference)
//
#include <hip/hip_runtime.h>

#define BB   128   // batch
#define TT   1024  // time steps
#define INP  256   // input dim
#define HH   512   // hidden dim
#define OUTD 256   // output dim
#define GB   16    // batches per group (group = XCD)
#define NG   8     // groups = XCDs
#define NBLK 256   // 1 per CU (88KB LDS cap) -> bijection -> 32 blocks/XCD

typedef float  f32x4  __attribute__((ext_vector_type(4)));
typedef short  short8 __attribute__((ext_vector_type(8)));
typedef unsigned long long u64;

__device__ __forceinline__ unsigned short bf16_rne(float f) {
  union { float f; unsigned u; } v; v.f = f;
  unsigned r = v.u + 0x7fffu + ((v.u >> 16) & 1u);
  return (unsigned short)(r >> 16);
}

__device__ __forceinline__ short8 pack8(f32x4 a, f32x4 b) {
  union { unsigned short s[8]; short8 v; } u;
  u.s[0] = bf16_rne(a[0]); u.s[1] = bf16_rne(a[1]);
  u.s[2] = bf16_rne(a[2]); u.s[3] = bf16_rne(a[3]);
  u.s[4] = bf16_rne(b[0]); u.s[5] = bf16_rne(b[1]);
  u.s[6] = bf16_rne(b[2]); u.s[7] = bf16_rne(b[3]);
  return u.v;
}

__device__ __forceinline__ short8 load_cvt8(const float* p) {
  const f32x4* q = (const f32x4*)p;
  return pack8(q[0], q[1]);
}

__device__ __forceinline__ f32x4 ntload4(const float* p) {
  return __builtin_nontemporal_load((const f32x4*)p);
}

// ---- XCD-local L2 h-state access. All producers/consumers of a group are on
// ONE XCD (ticket scheme below), so plain writeback stores + sc0 (L1-bypass)
// volatile loads are coherent through the local L2. No sc1, no MALL, no fences.
__device__ __forceinline__ short8 l2load8(const unsigned short* p) {
  union { u64 q[2]; short8 v; } u;
  const volatile u64* pp = (const volatile u64*)p;
  u.q[0] = pp[0];
  u.q[1] = pp[1];
  return u.v;
}

// Group barrier, XCD-local: arrival = workgroup-scope RMW (executes in the
// local XCD L2, no sc1/MALL); poll = volatile (sc0) load of the same L2 line.
// __syncthreads at entry drains vmcnt, so all h stores are in L2 before the add.
__device__ __forceinline__ void gbar(unsigned* cnt, unsigned target) {
  __syncthreads();
  if (threadIdx.x == 0) {
    __hip_atomic_fetch_add(cnt, 1u, __ATOMIC_RELAXED, __HIP_MEMORY_SCOPE_WORKGROUP);
    while (*(volatile unsigned*)cnt < target)
      __builtin_amdgcn_s_sleep(1);
  }
  __syncthreads();
}

// h-state fragment slots: per (slot, group): [kb(16)][lane(64)][e(8)] bf16 = 16KB.
// Value (b_local, j): kb = j>>5, lane' = ((j>>3)&3)*16 + b_local, e = j&7.
// 4-slot rings: max writer/reader tick distance 2 (< 4). Validated R5.
__device__ __forceinline__ unsigned short* hslot(unsigned short* base, int slot, int g) {
  return base + ((size_t)(slot * NG + g)) * (16 * 64 * 8);
}

__global__ void __launch_bounds__(256, 1) rnn_mfma(
    const float* __restrict__ x,       // [B][T][IN]
    const float* __restrict__ h0init,  // [2][B][H]
    const float* __restrict__ w_ih0,   // [H][IN]
    const float* __restrict__ w_hh0,   // [H][H]
    const float* __restrict__ b_ih0,   // [H]
    const float* __restrict__ b_hh0,   // [H]
    const float* __restrict__ w_ih1,   // [H][H]
    const float* __restrict__ w_hh1,   // [H][H]
    const float* __restrict__ b_ih1,   // [H]
    const float* __restrict__ b_hh1,   // [H]
    const float* __restrict__ fc_w,    // [OUT][H]
    const float* __restrict__ fc_b,    // [OUT]
    float* __restrict__ out,           // [B][OUT]
    unsigned* __restrict__ ws_ctl,     // [0..127]: tickets (8x16 u32); [128..255]: bar (8x16)
    unsigned short* __restrict__ h0f,  // h0 ring: 4 slots x NG x 16KB
    unsigned short* __restrict__ h1f)  // h1 ring: 4 slots x NG x 16KB
{
  extern __shared__ char lds_pad[];    // 88KB dynamic -> 1 block/CU (occupancy cap)
  (void)lds_pad;
  const int tid = threadIdx.x;

  // ---- claim a role on THIS XCD. 256 blocks @ 1/CU = bijection onto 256 CUs
  // -> exactly 32 blocks/XCD -> each XCD pool gets 32 claimants, 16 win.
  __shared__ unsigned sh_tk, sh_g;
  if (tid == 0) {
    unsigned xcc;
    asm volatile("s_getreg_b32 %0, hwreg(HW_REG_XCC_ID)" : "=s"(xcc));
    xcc &= 7;
    sh_g  = xcc;
    sh_tk = __hip_atomic_fetch_add(ws_ctl + xcc * 16, 1u,
                                   __ATOMIC_RELAXED, __HIP_MEMORY_SCOPE_AGENT);
  }
  __syncthreads();
  const unsigned ticket = sh_tk;
  const int g = (int)sh_g;
  if (ticket >= 16) return;            // spare blocks exit; never referenced

  const int role = (int)ticket;        // 0..7: L0 j-slices; 8..15: L1 j-slices
  const bool isL0 = role < 8;
  const int wv   = tid >> 6;
  const int lane = tid & 63;
  const int ln   = lane & 15;          // A-row (batch) / B-col (j)
  const int q    = lane >> 4;          // quad
  const int j0   = (role & 7) * 64 + wv * 16 + ln;  // output column
  const int bg   = g * GB;
  unsigned* cnt  = ws_ctl + 128 + g * 16;
  unsigned phase = 0;

  // ---- init: h0init -> h0 slot 3, h1init -> h1 slot 3 (plain stores, local L2).
  // Redundant across the group's 16 blocks; identical values, benign.
  for (int c = tid; c < 2048; c += 256) {
    int a  = c >> 10;            // 0 -> h0, 1 -> h1
    int bl = (c >> 6) & 15;
    int j8 = (c & 63) * 8;
    short8 v = load_cvt8(h0init + ((size_t)a * BB + (bg + bl)) * HH + j8);
    unsigned short* dst = hslot(a ? h1f : h0f, 3, g)
        + ((size_t)((j8 >> 5) * 64 + ((j8 >> 3) & 3) * 16 + bl)) * 8;
    *(short8*)dst = v;
  }

  // ---- weight B-fragments -> registers (once). Lane: row j0, k = kb*32+q*8+e.
  short8 Bf0[24];  // L0 only: w_ih0 (kb 0..7) then w_hh0 (kb 8..23)
  short8 Bf1[32];  // L1 only: w_ih1 (kb 0..15) then w_hh1 (kb 16..31)
  if (isL0) {
#pragma unroll
    for (int kb = 0; kb < 24; ++kb) {
      int k = kb * 32 + q * 8;
      const float* src = (k < INP) ? (w_ih0 + (size_t)j0 * INP + k)
                                   : (w_hh0 + (size_t)j0 * HH + (k - INP));
      Bf0[kb] = load_cvt8(src);
    }
  } else {
#pragma unroll
    for (int kb = 0; kb < 32; ++kb) {
      int k = kb * 32 + q * 8;
      const float* src = (k < HH) ? (w_ih1 + (size_t)j0 * HH + k)
                                  : (w_hh1 + (size_t)j0 * HH + (k - HH));
      Bf1[kb] = load_cvt8(src);
    }
  }
  const float bias = isL0 ? (b_ih0[j0] + b_hh0[j0]) : (b_ih1[j0] + b_hh1[j0]);

  // x(0) bf16 fragments (L0 only)
  short8 xa[8];
  if (isL0) {
    const float* xp = x + ((size_t)(bg + ln) * TT + 0) * INP;
#pragma unroll
    for (int kb = 0; kb < 8; ++kb)
      xa[kb] = pack8(ntload4(xp + kb * 32 + q * 8), ntload4(xp + kb * 32 + q * 8 + 4));
  }

  gbar(cnt, 16 * ++phase);

  const f32x4 z = {0.f, 0.f, 0.f, 0.f};

  // ---- tick loop: tick t: L0 computes h0(t) (t<TT); L1 computes h1(t-1) (t>=1).
  // One barrier per tick. h0(t-1) in slot (t+3)&3; h1(t-2) in (t+2)&3.
#pragma unroll 1
  for (int t = 0; t <= TT; ++t) {
    if (isL0) {
      if (t < TT) {
        const unsigned short* hp0 = hslot(h0f, (t + 3) & 3, g);  // h0(t-1)
        short8 Af[16];
#pragma unroll
        for (int kb = 0; kb < 16; ++kb)
          Af[kb] = l2load8(hp0 + ((size_t)kb * 64 + lane) * 8);

        f32x4 ac[4] = {z, z, z, z};
#pragma unroll
        for (int kb = 0; kb < 8; ++kb)
          ac[kb & 3] = __builtin_amdgcn_mfma_f32_16x16x32_bf16(
              xa[kb], Bf0[kb], ac[kb & 3], 0, 0, 0);
#pragma unroll
        for (int kb = 8; kb < 24; ++kb)
          ac[kb & 3] = __builtin_amdgcn_mfma_f32_16x16x32_bf16(
              Af[kb - 8], Bf0[kb], ac[kb & 3], 0, 0, 0);

        f32x4 d;
        d[0] = ac[0][0] + ac[1][0] + ac[2][0] + ac[3][0];
        d[1] = ac[0][1] + ac[1][1] + ac[2][1] + ac[3][1];
        d[2] = ac[0][2] + ac[1][2] + ac[2][2] + ac[3][2];
        d[3] = ac[0][3] + ac[1][3] + ac[2][3] + ac[3][3];
        unsigned short* wdst = hslot(h0f, t & 3, g);
#pragma unroll
        for (int r = 0; r < 4; ++r) {
          float v = tanhf(d[r] + bias);
          wdst[((size_t)((j0 >> 5) * 64 + ((j0 >> 3) & 3) * 16 + q * 4 + r)) * 8
               + (j0 & 7)] = bf16_rne(v);
        }
        // next tick's x: NT loads at tail; barrier vmcnt(0) drain covers them.
        if (t + 1 < TT) {
          const float* xp = x + ((size_t)(bg + ln) * TT + (t + 1)) * INP;
          f32x4 xr[16];
#pragma unroll
          for (int kb = 0; kb < 8; ++kb) {
            xr[2 * kb]     = ntload4(xp + kb * 32 + q * 8);
            xr[2 * kb + 1] = ntload4(xp + kb * 32 + q * 8 + 4);
          }
#pragma unroll
          for (int kb = 0; kb < 8; ++kb)
            xa[kb] = pack8(xr[2 * kb], xr[2 * kb + 1]);
        }
      }
    } else {
      if (t >= 1) {
        const unsigned short* hp0 = hslot(h0f, (t + 3) & 3, g);  // h0(t-1)
        const unsigned short* hp1 = hslot(h1f, (t + 2) & 3, g);  // h1(t-2)
        f32x4 ac[4] = {z, z, z, z};
        {
          short8 Af[16];
#pragma unroll
          for (int kb = 0; kb < 16; ++kb)
            Af[kb] = l2load8(hp0 + ((size_t)kb * 64 + lane) * 8);
#pragma unroll
          for (int kb = 0; kb < 16; ++kb)
            ac[kb & 3] = __builtin_amdgcn_mfma_f32_16x16x32_bf16(
                Af[kb], Bf1[kb], ac[kb & 3], 0, 0, 0);
        }
        {
          short8 Af[16];
#pragma unroll
          for (int kb = 0; kb < 16; ++kb)
            Af[kb] = l2load8(hp1 + ((size_t)kb * 64 + lane) * 8);
#pragma unroll
          for (int kb = 0; kb < 16; ++kb)
            ac[kb & 3] = __builtin_amdgcn_mfma_f32_16x16x32_bf16(
                Af[kb], Bf1[kb + 16], ac[kb & 3], 0, 0, 0);
        }
        f32x4 d;
        d[0] = ac[0][0] + ac[1][0] + ac[2][0] + ac[3][0];
        d[1] = ac[0][1] + ac[1][1] + ac[2][1] + ac[3][1];
        d[2] = ac[0][2] + ac[1][2] + ac[2][2] + ac[3][2];
        d[3] = ac[0][3] + ac[1][3] + ac[2][3] + ac[3][3];
        unsigned short* wdst = hslot(h1f, (t + 3) & 3, g);  // h1(t-1)
#pragma unroll
        for (int r = 0; r < 4; ++r) {
          float v = tanhf(d[r] + bias);
          wdst[((size_t)((j0 >> 5) * 64 + ((j0 >> 3) & 3) * 16 + q * 4 + r)) * 8
               + (j0 & 7)] = bf16_rne(v);
        }
      }
    }
    gbar(cnt, 16 * ++phase);
  }

  // ---- FC epilogue: out = h1(TT-1) @ fc_w^T + fc_b. h1(1023) in slot 3.
  if (wv == 0) {
    const unsigned short* hp = hslot(h1f, 3, g);
    const int o = role * 16 + ln;
    f32x4 ac[4] = {z, z, z, z};
#pragma unroll
    for (int kb = 0; kb < 16; ++kb) {
      int k = kb * 32 + q * 8;
      short8 Bfc = load_cvt8(fc_w + (size_t)o * HH + k);
      short8 Af  = l2load8(hp + ((size_t)kb * 64 + lane) * 8);
      ac[kb & 3] = __builtin_amdgcn_mfma_f32_16x16x32_bf16(
          Af, Bfc, ac[kb & 3], 0, 0, 0);
    }
    const float fb = fc_b[o];
#pragma unroll
    for (int r = 0; r < 4; ++r) {
      float v = ac[0][r] + ac[1][r] + ac[2][r] + ac[3][r] + fb;
      out[(size_t)(bg + q * 4 + r) * OUTD + o] = v;
    }
  }
}

extern "C" void kernel_launch(void* const* d_in, const int* in_sizes, int n_in,
                              void* d_out, int out_size, void* d_ws, size_t ws_size,
                              hipStream_t stream) {
  (void)in_sizes; (void)n_in; (void)out_size; (void)ws_size;

  const float* x      = (const float*)d_in[0];
  const float* h0init = (const float*)d_in[1];
  const float* w_ih0  = (const float*)d_in[2];
  const float* w_hh0  = (const float*)d_in[3];
  const float* b_ih0  = (const float*)d_in[4];
  const float* b_hh0  = (const float*)d_in[5];
  const float* w_ih1  = (const float*)d_in[6];
  const float* w_hh1  = (const float*)d_in[7];
  const float* b_ih1  = (const float*)d_in[8];
  const float* b_hh1  = (const float*)d_in[9];
  const float* fc_w   = (const float*)d_in[10];
  const float* fc_b   = (const float*)d_in[11];
  float* out = (float*)d_out;

  // ws: [0,1024) tickets+barrier counters (zeroed); [4096,...) h rings
  unsigned* ws_ctl = (unsigned*)d_ws;
  unsigned short* h0f = (unsigned short*)((char*)d_ws + 4096);
  unsigned short* h1f = h0f + 4 * NG * (16 * 64 * 8);

  hipMemsetAsync(d_ws, 0, 4096, stream);

  // 88KB dynamic LDS: caps occupancy at 1 block/CU -> 256 blocks occupy all
  // 256 CUs (bijection) -> exactly 32 blocks per XCD for the ticket scheme.
  rnn_mfma<<<dim3(NBLK), dim3(256), 90112, stream>>>(
      x, h0init, w_ih0, w_hh0, b_ih0, b_hh0, w_ih1, w_hh1, b_ih1, b_hh1,
      fc_w, fc_b, out, ws_ctl, h0f, h1f);
}

// Round 7
// 7721.367 us; speedup vs baseline: 1.0610x; 1.0610x over previous
//
#include <hip/hip_runtime.h>

#define BB   128   // batch
#define TT   1024  // time steps
#define INP  256   // input dim
#define HH   512   // hidden dim
#define OUTD 256   // output dim
#define GB   16    // batches per group (group = XCD)
#define NG   8     // groups = XCDs
#define NBLK 256   // 1 per CU (88KB LDS cap) -> bijection -> 32 blocks/XCD

typedef float  f32x4  __attribute__((ext_vector_type(4)));
typedef short  short8 __attribute__((ext_vector_type(8)));
typedef unsigned long long u64;

__device__ __forceinline__ unsigned short bf16_rne(float f) {
  union { float f; unsigned u; } v; v.f = f;
  unsigned r = v.u + 0x7fffu + ((v.u >> 16) & 1u);
  return (unsigned short)(r >> 16);
}

__device__ __forceinline__ short8 pack8(f32x4 a, f32x4 b) {
  union { unsigned short s[8]; short8 v; } u;
  u.s[0] = bf16_rne(a[0]); u.s[1] = bf16_rne(a[1]);
  u.s[2] = bf16_rne(a[2]); u.s[3] = bf16_rne(a[3]);
  u.s[4] = bf16_rne(b[0]); u.s[5] = bf16_rne(b[1]);
  u.s[6] = bf16_rne(b[2]); u.s[7] = bf16_rne(b[3]);
  return u.v;
}

__device__ __forceinline__ short8 load_cvt8(const float* p) {
  const f32x4* q = (const f32x4*)p;
  return pack8(q[0], q[1]);
}

__device__ __forceinline__ f32x4 ntload4(const float* p) {
  return __builtin_nontemporal_load((const f32x4*)p);
}

// XCD-local L2 h-state load: volatile (sc0, L1-bypass) hits the local XCD L2
// where the group's plain writeback stores land. Proven correct in R6.
__device__ __forceinline__ short8 l2load8(const unsigned short* p) {
  union { u64 q[2]; short8 v; } u;
  const volatile u64* pp = (const volatile u64*)p;
  u.q[0] = pp[0];
  u.q[1] = pp[1];
  return u.v;
}

// h-state fragment slots: per (slot, group): [kb(16)][lane(64)][e(8)] bf16 = 16KB.
// Value (b_local, j): kb = j>>5, lane' = ((j>>3)&3)*16 + b_local, e = j&7.
// 4-slot rings. Writer/reader distance bounds under flag scheme: L0-peer lead
// <=1 tick, L0-over-L1 lead <=3 ticks -> no slot collision (checked mod 4).
__device__ __forceinline__ unsigned short* hslot(unsigned short* base, int slot, int g) {
  return base + ((size_t)(slot * NG + g)) * (16 * 64 * 8);
}

__global__ void __launch_bounds__(256, 1) rnn_mfma(
    const float* __restrict__ x,       // [B][T][IN]
    const float* __restrict__ h0init,  // [2][B][H]
    const float* __restrict__ w_ih0,   // [H][IN]
    const float* __restrict__ w_hh0,   // [H][H]
    const float* __restrict__ b_ih0,   // [H]
    const float* __restrict__ b_hh0,   // [H]
    const float* __restrict__ w_ih1,   // [H][H]
    const float* __restrict__ w_hh1,   // [H][H]
    const float* __restrict__ b_ih1,   // [H]
    const float* __restrict__ b_hh1,   // [H]
    const float* __restrict__ fc_w,    // [OUT][H]
    const float* __restrict__ fc_b,    // [OUT]
    float* __restrict__ out,           // [B][OUT]
    unsigned* __restrict__ ws_ctl,     // tickets: [g*32]; flags: +1024 u32, per group 16 x 128B
    unsigned short* __restrict__ h0f,  // h0 ring: 4 slots x NG x 16KB
    unsigned short* __restrict__ h1f)  // h1 ring: 4 slots x NG x 16KB
{
  extern __shared__ char lds_pad[];    // 88KB dynamic -> 1 block/CU
  (void)lds_pad;
  const int tid = threadIdx.x;

  // ---- claim a role on THIS XCD (R6-proven). 256 blocks @1/CU -> 32/XCD.
  __shared__ unsigned sh_tk, sh_g;
  if (tid == 0) {
    unsigned xcc;
    asm volatile("s_getreg_b32 %0, hwreg(HW_REG_XCC_ID)" : "=s"(xcc));
    xcc &= 7;
    sh_g  = xcc;
    sh_tk = __hip_atomic_fetch_add(ws_ctl + xcc * 32, 1u,
                                   __ATOMIC_RELAXED, __HIP_MEMORY_SCOPE_AGENT);
  }
  __syncthreads();
  const unsigned ticket = sh_tk;
  const int g = (int)sh_g;
  if (ticket >= 16) return;            // spares exit

  const int role = (int)ticket;        // 0..7: L0 j-slices; 8..15: L1 j-slices
  const bool isL0 = role < 8;
  const int wv   = tid >> 6;
  const int lane = tid & 63;
  const int ln   = lane & 15;
  const int q    = lane >> 4;
  const int j0   = (role & 7) * 64 + wv * 16 + ln;
  const int bg   = g * GB;

  // Per-block flag lines: flag[b] = 1 after init; = t+2 after completing tick t.
  // Single writer per line; no RMW, no shared-line contention.
  volatile int* flags  = (volatile int*)(ws_ctl + 1024 + g * 512);
  volatile int* myflag = flags + role * 32;

  // ---- init: h0init -> h0 slot 3, h1init -> h1 slot 3 (plain stores, local L2).
  for (int c = tid; c < 2048; c += 256) {
    int a  = c >> 10;
    int bl = (c >> 6) & 15;
    int j8 = (c & 63) * 8;
    short8 v = load_cvt8(h0init + ((size_t)a * BB + (bg + bl)) * HH + j8);
    unsigned short* dst = hslot(a ? h1f : h0f, 3, g)
        + ((size_t)((j8 >> 5) * 64 + ((j8 >> 3) & 3) * 16 + bl)) * 8;
    *(short8*)dst = v;
  }
  __syncthreads();                     // drain init stores to L2
  if (tid == 0) *myflag = 1;           // init published

  // ---- weight B-fragments -> registers. Lane: row j0, k = kb*32+q*8+e.
  short8 Bf0[24];  // L0: w_ih0 (kb 0..7) then w_hh0 (kb 8..23)
  short8 Bf1[32];  // L1: w_ih1 (kb 0..15) then w_hh1 (kb 16..31)
  if (isL0) {
#pragma unroll
    for (int kb = 0; kb < 24; ++kb) {
      int k = kb * 32 + q * 8;
      const float* src = (k < INP) ? (w_ih0 + (size_t)j0 * INP + k)
                                   : (w_hh0 + (size_t)j0 * HH + (k - INP));
      Bf0[kb] = load_cvt8(src);
    }
  } else {
#pragma unroll
    for (int kb = 0; kb < 32; ++kb) {
      int k = kb * 32 + q * 8;
      const float* src = (k < HH) ? (w_ih1 + (size_t)j0 * HH + k)
                                  : (w_hh1 + (size_t)j0 * HH + (k - HH));
      Bf1[kb] = load_cvt8(src);
    }
  }
  const float bias = isL0 ? (b_ih0[j0] + b_hh0[j0]) : (b_ih1[j0] + b_hh1[j0]);

  short8 xa[8];
  if (isL0) {
    const float* xp = x + ((size_t)(bg + ln) * TT + 0) * INP;
#pragma unroll
    for (int kb = 0; kb < 8; ++kb)
      xa[kb] = pack8(ntload4(xp + kb * 32 + q * 8), ntload4(xp + kb * 32 + q * 8 + 4));
  }

  const f32x4 z = {0.f, 0.f, 0.f, 0.f};
  const int tmax = isL0 ? (TT - 1) : TT;

  // ---- tick loop. L0 tick t: h0(t) = f(x(t), h0(t-1)). Waits: L0 flags >= t+1
  // (producers of h0(t-1)), L1 flags >= t-1 (slot-reuse safety; 2-tick slack).
  // L1 tick t (>=1): h1(t-1) = f(h0(t-1), h1(t-2)). Waits: L0,L1 flags >= t+1.
#pragma unroll 1
  for (int t = 0; t <= tmax; ++t) {
    {
      const int thrL0 = t + 1;
      const int thrL1 = isL0 ? (t - 1) : (t + 1);
      if (tid < 16) {
        volatile int* fp = flags + tid * 32;
        const int thr = (tid < 8) ? thrL0 : thrL1;
        while (*fp < thr) __builtin_amdgcn_s_sleep(2);
      }
      __syncthreads();
    }

    if (isL0) {
      const unsigned short* hp0 = hslot(h0f, (t + 3) & 3, g);  // h0(t-1)
      short8 Af[16];
#pragma unroll
      for (int kb = 0; kb < 16; ++kb)
        Af[kb] = l2load8(hp0 + ((size_t)kb * 64 + lane) * 8);

      // x(t+1) NT loads issued early: complete during MFMAs
      f32x4 xr[16];
      if (t + 1 < TT) {
        const float* xp = x + ((size_t)(bg + ln) * TT + (t + 1)) * INP;
#pragma unroll
        for (int kb = 0; kb < 8; ++kb) {
          xr[2 * kb]     = ntload4(xp + kb * 32 + q * 8);
          xr[2 * kb + 1] = ntload4(xp + kb * 32 + q * 8 + 4);
        }
      }

      f32x4 ac[4] = {z, z, z, z};
#pragma unroll
      for (int kb = 0; kb < 8; ++kb)
        ac[kb & 3] = __builtin_amdgcn_mfma_f32_16x16x32_bf16(
            xa[kb], Bf0[kb], ac[kb & 3], 0, 0, 0);
#pragma unroll
      for (int kb = 8; kb < 24; ++kb)
        ac[kb & 3] = __builtin_amdgcn_mfma_f32_16x16x32_bf16(
            Af[kb - 8], Bf0[kb], ac[kb & 3], 0, 0, 0);

      f32x4 d;
      d[0] = ac[0][0] + ac[1][0] + ac[2][0] + ac[3][0];
      d[1] = ac[0][1] + ac[1][1] + ac[2][1] + ac[3][1];
      d[2] = ac[0][2] + ac[1][2] + ac[2][2] + ac[3][2];
      d[3] = ac[0][3] + ac[1][3] + ac[2][3] + ac[3][3];
      unsigned short* wdst = hslot(h0f, t & 3, g);
#pragma unroll
      for (int r = 0; r < 4; ++r) {
        float v = tanhf(d[r] + bias);
        wdst[((size_t)((j0 >> 5) * 64 + ((j0 >> 3) & 3) * 16 + q * 4 + r)) * 8
             + (j0 & 7)] = bf16_rne(v);
      }
      if (t + 1 < TT) {
#pragma unroll
        for (int kb = 0; kb < 8; ++kb)
          xa[kb] = pack8(xr[2 * kb], xr[2 * kb + 1]);
      }
    } else if (t >= 1) {
      const unsigned short* hp0 = hslot(h0f, (t + 3) & 3, g);  // h0(t-1)
      const unsigned short* hp1 = hslot(h1f, (t + 2) & 3, g);  // h1(t-2)
      f32x4 ac[4] = {z, z, z, z};
      {
        short8 Af[16];
#pragma unroll
        for (int kb = 0; kb < 16; ++kb)
          Af[kb] = l2load8(hp0 + ((size_t)kb * 64 + lane) * 8);
#pragma unroll
        for (int kb = 0; kb < 16; ++kb)
          ac[kb & 3] = __builtin_amdgcn_mfma_f32_16x16x32_bf16(
              Af[kb], Bf1[kb], ac[kb & 3], 0, 0, 0);
      }
      {
        short8 Af[16];
#pragma unroll
        for (int kb = 0; kb < 16; ++kb)
          Af[kb] = l2load8(hp1 + ((size_t)kb * 64 + lane) * 8);
#pragma unroll
        for (int kb = 0; kb < 16; ++kb)
          ac[kb & 3] = __builtin_amdgcn_mfma_f32_16x16x32_bf16(
              Af[kb], Bf1[kb + 16], ac[kb & 3], 0, 0, 0);
      }
      f32x4 d;
      d[0] = ac[0][0] + ac[1][0] + ac[2][0] + ac[3][0];
      d[1] = ac[0][1] + ac[1][1] + ac[2][1] + ac[3][1];
      d[2] = ac[0][2] + ac[1][2] + ac[2][2] + ac[3][2];
      d[3] = ac[0][3] + ac[1][3] + ac[2][3] + ac[3][3];
      unsigned short* wdst = hslot(h1f, (t + 3) & 3, g);  // h1(t-1)
#pragma unroll
      for (int r = 0; r < 4; ++r) {
        float v = tanhf(d[r] + bias);
        wdst[((size_t)((j0 >> 5) * 64 + ((j0 >> 3) & 3) * 16 + q * 4 + r)) * 8
             + (j0 & 7)] = bf16_rne(v);
      }
    }

    __syncthreads();                   // drain this tick's h stores to L2
    if (tid == 0) *myflag = t + 2;     // publish tick completion
  }

  // ---- FC epilogue: out = h1(TT-1) @ fc_w^T + fc_b (slot 3). Wait for all
  // L1 blocks to finish tick TT (flag = TT+2); L0 flags end at TT+1.
  if (tid < 16) {
    volatile int* fp = flags + tid * 32;
    const int thr = (tid < 8) ? (TT + 1) : (TT + 2);
    while (*fp < thr) __builtin_amdgcn_s_sleep(2);
  }
  __syncthreads();

  if (wv == 0) {
    const unsigned short* hp = hslot(h1f, 3, g);
    const int o = role * 16 + ln;
    f32x4 ac[4] = {z, z, z, z};
#pragma unroll
    for (int kb = 0; kb < 16; ++kb) {
      int k = kb * 32 + q * 8;
      short8 Bfc = load_cvt8(fc_w + (size_t)o * HH + k);
      short8 Af  = l2load8(hp + ((size_t)kb * 64 + lane) * 8);
      ac[kb & 3] = __builtin_amdgcn_mfma_f32_16x16x32_bf16(
          Af, Bfc, ac[kb & 3], 0, 0, 0);
    }
    const float fb = fc_b[o];
#pragma unroll
    for (int r = 0; r < 4; ++r) {
      float v = ac[0][r] + ac[1][r] + ac[2][r] + ac[3][r] + fb;
      out[(size_t)(bg + q * 4 + r) * OUTD + o] = v;
    }
  }
}

extern "C" void kernel_launch(void* const* d_in, const int* in_sizes, int n_in,
                              void* d_out, int out_size, void* d_ws, size_t ws_size,
                              hipStream_t stream) {
  (void)in_sizes; (void)n_in; (void)out_size; (void)ws_size;

  const float* x      = (const float*)d_in[0];
  const float* h0init = (const float*)d_in[1];
  const float* w_ih0  = (const float*)d_in[2];
  const float* w_hh0  = (const float*)d_in[3];
  const float* b_ih0  = (const float*)d_in[4];
  const float* b_hh0  = (const float*)d_in[5];
  const float* w_ih1  = (const float*)d_in[6];
  const float* w_hh1  = (const float*)d_in[7];
  const float* b_ih1  = (const float*)d_in[8];
  const float* b_hh1  = (const float*)d_in[9];
  const float* fc_w   = (const float*)d_in[10];
  const float* fc_b   = (const float*)d_in[11];
  float* out = (float*)d_out;

  // ws: [0,32768) tickets + flags (zeroed); then h0 ring 512KB; h1 ring 512KB
  unsigned* ws_ctl = (unsigned*)d_ws;
  unsigned short* h0f = (unsigned short*)((char*)d_ws + 32768);
  unsigned short* h1f = h0f + 4 * NG * (16 * 64 * 8);

  hipMemsetAsync(d_ws, 0, 32768, stream);

  // 88KB dynamic LDS: 1 block/CU -> 256 blocks = all CUs -> 32 blocks/XCD.
  rnn_mfma<<<dim3(NBLK), dim3(256), 90112, stream>>>(
      x, h0init, w_ih0, w_hh0, b_ih0, b_hh0, w_ih1, w_hh1, b_ih1, b_hh1,
      fc_w, fc_b, out, ws_ctl, h0f, h1f);
}

// Round 8
// 4868.164 us; speedup vs baseline: 1.6828x; 1.5861x over previous
//
#include <hip/hip_runtime.h>

#define BB   128   // batch
#define TT   1024  // time steps
#define INP  256   // input dim
#define HH   512   // hidden dim
#define OUTD 256   // output dim
#define GB   16    // batches per group (group = XCD)
#define NG   8     // groups = XCDs
#define NBLK 256   // 1 per CU (88KB LDS cap) -> bijection -> 32 blocks/XCD

typedef float  f32x4  __attribute__((ext_vector_type(4)));
typedef short  short8 __attribute__((ext_vector_type(8)));
typedef unsigned long long u64;

__device__ __forceinline__ unsigned short bf16_rne(float f) {
  union { float f; unsigned u; } v; v.f = f;
  unsigned r = v.u + 0x7fffu + ((v.u >> 16) & 1u);
  return (unsigned short)(r >> 16);
}

__device__ __forceinline__ short8 pack8(f32x4 a, f32x4 b) {
  union { unsigned short s[8]; short8 v; } u;
  u.s[0] = bf16_rne(a[0]); u.s[1] = bf16_rne(a[1]);
  u.s[2] = bf16_rne(a[2]); u.s[3] = bf16_rne(a[3]);
  u.s[4] = bf16_rne(b[0]); u.s[5] = bf16_rne(b[1]);
  u.s[6] = bf16_rne(b[2]); u.s[7] = bf16_rne(b[3]);
  return u.v;
}

__device__ __forceinline__ short8 load_cvt8(const float* p) {
  const f32x4* q = (const f32x4*)p;
  return pack8(q[0], q[1]);
}

__device__ __forceinline__ f32x4 ntload4(const float* p) {
  return __builtin_nontemporal_load((const f32x4*)p);
}

// XCD-local L2 h-state load. Agent-scope RELAXED atomic: emits sc0 (L1 bypass,
// reads the XCD L2 where the group's plain writeback stores land — same
// visibility as R6/R7's volatile loads) but is NOT volatile-ordered, so the
// compiler batches 16-32 outstanding loads with a single waitcnt before use.
// R6/R7's volatile version serialized each load (~350cyc x 32 = the whole tick).
__device__ __forceinline__ short8 l2load8(const unsigned short* p) {
  union { u64 q[2]; short8 v; } u;
  const u64* pp = (const u64*)p;
  u.q[0] = __hip_atomic_load(pp,     __ATOMIC_RELAXED, __HIP_MEMORY_SCOPE_AGENT);
  u.q[1] = __hip_atomic_load(pp + 1, __ATOMIC_RELAXED, __HIP_MEMORY_SCOPE_AGENT);
  return u.v;
}

// h-state fragment slots: per (slot, group): [kb(16)][lane(64)][e(8)] bf16 = 16KB.
// Value (b_local, j): kb = j>>5, lane' = ((j>>3)&3)*16 + b_local, e = j&7.
// 4-slot rings. Writer/reader distance bounds under flag scheme: L0-peer lead
// <=1 tick, L0-over-L1 lead <=3 ticks -> no slot collision (checked mod 4).
__device__ __forceinline__ unsigned short* hslot(unsigned short* base, int slot, int g) {
  return base + ((size_t)(slot * NG + g)) * (16 * 64 * 8);
}

__global__ void __launch_bounds__(256, 1) rnn_mfma(
    const float* __restrict__ x,       // [B][T][IN]
    const float* __restrict__ h0init,  // [2][B][H]
    const float* __restrict__ w_ih0,   // [H][IN]
    const float* __restrict__ w_hh0,   // [H][H]
    const float* __restrict__ b_ih0,   // [H]
    const float* __restrict__ b_hh0,   // [H]
    const float* __restrict__ w_ih1,   // [H][H]
    const float* __restrict__ w_hh1,   // [H][H]
    const float* __restrict__ b_ih1,   // [H]
    const float* __restrict__ b_hh1,   // [H]
    const float* __restrict__ fc_w,    // [OUT][H]
    const float* __restrict__ fc_b,    // [OUT]
    float* __restrict__ out,           // [B][OUT]
    unsigned* __restrict__ ws_ctl,     // tickets: [g*32]; flags: +1024 u32, per group 16 x 128B
    unsigned short* __restrict__ h0f,  // h0 ring: 4 slots x NG x 16KB
    unsigned short* __restrict__ h1f)  // h1 ring: 4 slots x NG x 16KB
{
  extern __shared__ char lds_pad[];    // 88KB dynamic -> occupancy cap
  (void)lds_pad;
  const int tid = threadIdx.x;

  // ---- claim a role on THIS XCD (R6-proven).
  __shared__ unsigned sh_tk, sh_g;
  if (tid == 0) {
    unsigned xcc;
    asm volatile("s_getreg_b32 %0, hwreg(HW_REG_XCC_ID)" : "=s"(xcc));
    xcc &= 7;
    sh_g  = xcc;
    sh_tk = __hip_atomic_fetch_add(ws_ctl + xcc * 32, 1u,
                                   __ATOMIC_RELAXED, __HIP_MEMORY_SCOPE_AGENT);
  }
  __syncthreads();
  const unsigned ticket = sh_tk;
  const int g = (int)sh_g;
  if (ticket >= 16) return;            // spares exit

  const int role = (int)ticket;        // 0..7: L0 j-slices; 8..15: L1 j-slices
  const bool isL0 = role < 8;
  const int wv   = tid >> 6;
  const int lane = tid & 63;
  const int ln   = lane & 15;
  const int q    = lane >> 4;
  const int j0   = (role & 7) * 64 + wv * 16 + ln;
  const int bg   = g * GB;

  // Per-block flag lines: flag[b] = 1 after init; = t+2 after completing tick t.
  volatile int* flags  = (volatile int*)(ws_ctl + 1024 + g * 512);
  volatile int* myflag = flags + role * 32;

  // ---- init: h0init -> h0 slot 3, h1init -> h1 slot 3 (plain stores, local L2).
  for (int c = tid; c < 2048; c += 256) {
    int a  = c >> 10;
    int bl = (c >> 6) & 15;
    int j8 = (c & 63) * 8;
    short8 v = load_cvt8(h0init + ((size_t)a * BB + (bg + bl)) * HH + j8);
    unsigned short* dst = hslot(a ? h1f : h0f, 3, g)
        + ((size_t)((j8 >> 5) * 64 + ((j8 >> 3) & 3) * 16 + bl)) * 8;
    *(short8*)dst = v;
  }
  __syncthreads();                     // drain init stores to L2
  if (tid == 0) *myflag = 1;           // init published

  // ---- weight B-fragments -> registers. Lane: row j0, k = kb*32+q*8+e.
  short8 Bf0[24];  // L0: w_ih0 (kb 0..7) then w_hh0 (kb 8..23)
  short8 Bf1[32];  // L1: w_ih1 (kb 0..15) then w_hh1 (kb 16..31)
  if (isL0) {
#pragma unroll
    for (int kb = 0; kb < 24; ++kb) {
      int k = kb * 32 + q * 8;
      const float* src = (k < INP) ? (w_ih0 + (size_t)j0 * INP + k)
                                   : (w_hh0 + (size_t)j0 * HH + (k - INP));
      Bf0[kb] = load_cvt8(src);
    }
  } else {
#pragma unroll
    for (int kb = 0; kb < 32; ++kb) {
      int k = kb * 32 + q * 8;
      const float* src = (k < HH) ? (w_ih1 + (size_t)j0 * HH + k)
                                  : (w_hh1 + (size_t)j0 * HH + (k - HH));
      Bf1[kb] = load_cvt8(src);
    }
  }
  const float bias = isL0 ? (b_ih0[j0] + b_hh0[j0]) : (b_ih1[j0] + b_hh1[j0]);

  short8 xa[8];
  if (isL0) {
    const float* xp = x + ((size_t)(bg + ln) * TT + 0) * INP;
#pragma unroll
    for (int kb = 0; kb < 8; ++kb)
      xa[kb] = pack8(ntload4(xp + kb * 32 + q * 8), ntload4(xp + kb * 32 + q * 8 + 4));
  }

  const f32x4 z = {0.f, 0.f, 0.f, 0.f};
  const int tmax = isL0 ? (TT - 1) : TT;

  // ---- tick loop. L0 tick t: h0(t) = f(x(t), h0(t-1)). Waits: L0 flags >= t+1,
  // L1 flags >= t-1 (slot-reuse guard). L1 tick t (>=1): h1(t-1) =
  // f(h0(t-1), h1(t-2)). Waits: L0,L1 flags >= t+1.
#pragma unroll 1
  for (int t = 0; t <= tmax; ++t) {
    {
      const int thrL0 = t + 1;
      const int thrL1 = isL0 ? (t - 1) : (t + 1);
      if (tid < 16) {
        volatile int* fp = flags + tid * 32;
        const int thr = (tid < 8) ? thrL0 : thrL1;
        while (*fp < thr) __builtin_amdgcn_s_sleep(1);
      }
      __syncthreads();
    }

    if (isL0) {
      const unsigned short* hp0 = hslot(h0f, (t + 3) & 3, g);  // h0(t-1)
      short8 Af[16];
#pragma unroll
      for (int kb = 0; kb < 16; ++kb)
        Af[kb] = l2load8(hp0 + ((size_t)kb * 64 + lane) * 8);

      // x(t+1) NT loads issued early: complete during MFMAs
      f32x4 xr[16];
      if (t + 1 < TT) {
        const float* xp = x + ((size_t)(bg + ln) * TT + (t + 1)) * INP;
#pragma unroll
        for (int kb = 0; kb < 8; ++kb) {
          xr[2 * kb]     = ntload4(xp + kb * 32 + q * 8);
          xr[2 * kb + 1] = ntload4(xp + kb * 32 + q * 8 + 4);
        }
      }

      f32x4 ac[4] = {z, z, z, z};
#pragma unroll
      for (int kb = 0; kb < 8; ++kb)
        ac[kb & 3] = __builtin_amdgcn_mfma_f32_16x16x32_bf16(
            xa[kb], Bf0[kb], ac[kb & 3], 0, 0, 0);
#pragma unroll
      for (int kb = 8; kb < 24; ++kb)
        ac[kb & 3] = __builtin_amdgcn_mfma_f32_16x16x32_bf16(
            Af[kb - 8], Bf0[kb], ac[kb & 3], 0, 0, 0);

      f32x4 d;
      d[0] = ac[0][0] + ac[1][0] + ac[2][0] + ac[3][0];
      d[1] = ac[0][1] + ac[1][1] + ac[2][1] + ac[3][1];
      d[2] = ac[0][2] + ac[1][2] + ac[2][2] + ac[3][2];
      d[3] = ac[0][3] + ac[1][3] + ac[2][3] + ac[3][3];
      unsigned short* wdst = hslot(h0f, t & 3, g);
#pragma unroll
      for (int r = 0; r < 4; ++r) {
        float v = tanhf(d[r] + bias);
        wdst[((size_t)((j0 >> 5) * 64 + ((j0 >> 3) & 3) * 16 + q * 4 + r)) * 8
             + (j0 & 7)] = bf16_rne(v);
      }
      if (t + 1 < TT) {
#pragma unroll
        for (int kb = 0; kb < 8; ++kb)
          xa[kb] = pack8(xr[2 * kb], xr[2 * kb + 1]);
      }
    } else if (t >= 1) {
      const unsigned short* hp0 = hslot(h0f, (t + 3) & 3, g);  // h0(t-1)
      const unsigned short* hp1 = hslot(h1f, (t + 2) & 3, g);  // h1(t-2)
      // batch ALL 32 A-frag loads before any MFMA (one waitcnt, pipelined)
      short8 Af0[16], Af1[16];
#pragma unroll
      for (int kb = 0; kb < 16; ++kb)
        Af0[kb] = l2load8(hp0 + ((size_t)kb * 64 + lane) * 8);
#pragma unroll
      for (int kb = 0; kb < 16; ++kb)
        Af1[kb] = l2load8(hp1 + ((size_t)kb * 64 + lane) * 8);

      f32x4 ac[4] = {z, z, z, z};
#pragma unroll
      for (int kb = 0; kb < 16; ++kb)
        ac[kb & 3] = __builtin_amdgcn_mfma_f32_16x16x32_bf16(
            Af0[kb], Bf1[kb], ac[kb & 3], 0, 0, 0);
#pragma unroll
      for (int kb = 0; kb < 16; ++kb)
        ac[kb & 3] = __builtin_amdgcn_mfma_f32_16x16x32_bf16(
            Af1[kb], Bf1[kb + 16], ac[kb & 3], 0, 0, 0);

      f32x4 d;
      d[0] = ac[0][0] + ac[1][0] + ac[2][0] + ac[3][0];
      d[1] = ac[0][1] + ac[1][1] + ac[2][1] + ac[3][1];
      d[2] = ac[0][2] + ac[1][2] + ac[2][2] + ac[3][2];
      d[3] = ac[0][3] + ac[1][3] + ac[2][3] + ac[3][3];
      unsigned short* wdst = hslot(h1f, (t + 3) & 3, g);  // h1(t-1)
#pragma unroll
      for (int r = 0; r < 4; ++r) {
        float v = tanhf(d[r] + bias);
        wdst[((size_t)((j0 >> 5) * 64 + ((j0 >> 3) & 3) * 16 + q * 4 + r)) * 8
             + (j0 & 7)] = bf16_rne(v);
      }
    }

    __syncthreads();                   // drain this tick's h stores to L2
    if (tid == 0) *myflag = t + 2;     // publish tick completion
  }

  // ---- FC epilogue: out = h1(TT-1) @ fc_w^T + fc_b (slot 3). Wait for all
  // L1 blocks to finish tick TT (flag = TT+2); L0 flags end at TT+1.
  if (tid < 16) {
    volatile int* fp = flags + tid * 32;
    const int thr = (tid < 8) ? (TT + 1) : (TT + 2);
    while (*fp < thr) __builtin_amdgcn_s_sleep(1);
  }
  __syncthreads();

  if (wv == 0) {
    const unsigned short* hp = hslot(h1f, 3, g);
    const int o = role * 16 + ln;
    f32x4 ac[4] = {z, z, z, z};
#pragma unroll
    for (int kb = 0; kb < 16; ++kb) {
      int k = kb * 32 + q * 8;
      short8 Bfc = load_cvt8(fc_w + (size_t)o * HH + k);
      short8 Af  = l2load8(hp + ((size_t)kb * 64 + lane) * 8);
      ac[kb & 3] = __builtin_amdgcn_mfma_f32_16x16x32_bf16(
          Af, Bfc, ac[kb & 3], 0, 0, 0);
    }
    const float fb = fc_b[o];
#pragma unroll
    for (int r = 0; r < 4; ++r) {
      float v = ac[0][r] + ac[1][r] + ac[2][r] + ac[3][r] + fb;
      out[(size_t)(bg + q * 4 + r) * OUTD + o] = v;
    }
  }
}

extern "C" void kernel_launch(void* const* d_in, const int* in_sizes, int n_in,
                              void* d_out, int out_size, void* d_ws, size_t ws_size,
                              hipStream_t stream) {
  (void)in_sizes; (void)n_in; (void)out_size; (void)ws_size;

  const float* x      = (const float*)d_in[0];
  const float* h0init = (const float*)d_in[1];
  const float* w_ih0  = (const float*)d_in[2];
  const float* w_hh0  = (const float*)d_in[3];
  const float* b_ih0  = (const float*)d_in[4];
  const float* b_hh0  = (const float*)d_in[5];
  const float* w_ih1  = (const float*)d_in[6];
  const float* w_hh1  = (const float*)d_in[7];
  const float* b_ih1  = (const float*)d_in[8];
  const float* b_hh1  = (const float*)d_in[9];
  const float* fc_w   = (const float*)d_in[10];
  const float* fc_b   = (const float*)d_in[11];
  float* out = (float*)d_out;

  // ws: [0,32768) tickets + flags (zeroed); then h0 ring 512KB; h1 ring 512KB
  unsigned* ws_ctl = (unsigned*)d_ws;
  unsigned short* h0f = (unsigned short*)((char*)d_ws + 32768);
  unsigned short* h1f = h0f + 4 * NG * (16 * 64 * 8);

  hipMemsetAsync(d_ws, 0, 32768, stream);

  rnn_mfma<<<dim3(NBLK), dim3(256), 90112, stream>>>(
      x, h0init, w_ih0, w_hh0, b_ih0, b_hh0, w_ih1, w_hh1, b_ih1, b_hh1,
      fc_w, fc_b, out, ws_ctl, h0f, h1f);
}